// Round 2
// baseline (364.181 us; speedup 1.0000x reference)
//
#include <hip/hip_runtime.h>
#include <stdint.h>

#define T_TOK 4096
#define DM    512
#define DFF   2048
#define NE    16
#define NSLOT (T_TOK * 2)
#define NW    (NE * DFF * DM)   // 16,777,216 elems per weight tensor

typedef __attribute__((ext_vector_type(8))) short  bf16x8;
typedef __attribute__((ext_vector_type(4))) float  f32x4;
typedef __attribute__((ext_vector_type(8))) unsigned short us8;

static __device__ __forceinline__ unsigned short f2bf(float f) {
    unsigned int u = __float_as_uint(f);
    u += 0x7FFFu + ((u >> 16) & 1u);   // RNE
    return (unsigned short)(u >> 16);
}

static __device__ __forceinline__ void gload_lds16(const void* g, void* l) {
    __builtin_amdgcn_global_load_lds(
        (const __attribute__((address_space(1))) void*)g,
        (__attribute__((address_space(3))) void*)l, 16, 0, 0);
}

// ------------- convert: w1, w2, x fp32 -> bf16 (memory-bound) ------------
__global__ __launch_bounds__(256) void convert_kernel(
    const float* __restrict__ w1, const float* __restrict__ w2,
    const float* __restrict__ x, unsigned short* __restrict__ w1b,
    unsigned short* __restrict__ w2b, unsigned short* __restrict__ xb)
{
    size_t i = ((size_t)blockIdx.x * 256 + threadIdx.x) * 8;
    const float* src; unsigned short* dst;
    if (i < (size_t)NW)            { src = w1 + i;      dst = w1b + i; }
    else if (i < 2 * (size_t)NW)   { src = w2 + (i - NW); dst = w2b + (i - NW); }
    else {
        size_t o = i - 2 * (size_t)NW;
        if (o >= (size_t)T_TOK * DM) return;
        src = x + o; dst = xb + o;
    }
    f32x4 a = *(const f32x4*)src;
    f32x4 b = *(const f32x4*)(src + 4);
    us8 v;
    v[0] = f2bf(a.x); v[1] = f2bf(a.y); v[2] = f2bf(a.z); v[3] = f2bf(a.w);
    v[4] = f2bf(b.x); v[5] = f2bf(b.y); v[6] = f2bf(b.z); v[7] = f2bf(b.w);
    *(us8*)dst = v;
}

// ---------------- router: fp32 logits, softmax, top-2 --------------------
__global__ __launch_bounds__(256) void router_kernel(
    const float* __restrict__ x, const float* __restrict__ rw,
    const float* __restrict__ rb, int* __restrict__ tok_e,
    float* __restrict__ tok_g)
{
    __shared__ float rws[NE * DM];
    int tid = threadIdx.x;
    for (int i = 0; i < 8; ++i) {
        int idx = (tid + i * 256) * 4;
        *(f32x4*)&rws[idx] = *(const f32x4*)&rw[idx];
    }
    __syncthreads();

    int wid = tid >> 6, lane = tid & 63;
    int t = blockIdx.x * 4 + wid;

    float xv[8];
    const float* xp = x + (size_t)t * DM + lane * 8;
    *(f32x4*)&xv[0] = *(const f32x4*)xp;
    *(f32x4*)&xv[4] = *(const f32x4*)(xp + 4);

    float acc[NE];
    for (int e = 0; e < NE; ++e) {
        const float* wp = &rws[e * DM + lane * 8];
        float a = 0.f;
        for (int i = 0; i < 8; ++i) a += xv[i] * wp[i];
        acc[e] = a;
    }
    for (int e = 0; e < NE; ++e) {
        float v = acc[e];
        for (int off = 32; off > 0; off >>= 1) v += __shfl_xor(v, off);
        acc[e] = v + rb[e];
    }
    float m = acc[0];
    for (int e = 1; e < NE; ++e) m = fmaxf(m, acc[e]);
    float p[NE]; float s = 0.f;
    for (int e = 0; e < NE; ++e) { p[e] = expf(acc[e] - m); s += p[e]; }
    float inv = 1.f / s;
    int i0 = 0; float p0 = p[0];
    for (int e = 1; e < NE; ++e) if (p[e] > p0) { p0 = p[e]; i0 = e; }
    int i1 = (i0 == 0) ? 1 : 0; float p1 = p[i1];
    for (int e = 0; e < NE; ++e)
        if (e != i0 && p[e] > p1) { p1 = p[e]; i1 = e; }
    if (lane == 0) {
        tok_e[t * 2]     = i0;  tok_e[t * 2 + 1] = i1;
        tok_g[t * 2]     = p0 * inv;
        tok_g[t * 2 + 1] = p1 * inv;
    }
}

// ---------------- compaction: per-expert slot lists ----------------------
__global__ __launch_bounds__(256) void compact_kernel(
    const int* __restrict__ tok_e, const float* __restrict__ tok_g,
    int* __restrict__ slot_token, float* __restrict__ slot_gate,
    int* __restrict__ eoff)
{
    __shared__ int cnt[NE], cur[NE], offs[NE];
    int tid = threadIdx.x;
    if (tid < NE) cnt[tid] = 0;
    __syncthreads();
    for (int t = tid; t < T_TOK; t += 256) {
        atomicAdd(&cnt[tok_e[t * 2]], 1);
        atomicAdd(&cnt[tok_e[t * 2 + 1]], 1);
    }
    __syncthreads();
    if (tid == 0) {
        int r = 0;
        for (int e = 0; e < NE; ++e) { offs[e] = r; cur[e] = r; r += cnt[e]; }
    }
    __syncthreads();
    if (tid < NE) { eoff[tid] = offs[tid]; eoff[NE + tid] = cnt[tid]; }
    for (int t = tid; t < T_TOK; t += 256) {
        for (int k = 0; k < 2; ++k) {
            int e = tok_e[t * 2 + k];
            int s = atomicAdd(&cur[e], 1);
            slot_token[s] = t;
            slot_gate[s]  = tok_g[t * 2 + k];
        }
    }
}

// ------ GEMM1: h = gelu(x_bf[gather] @ w1b^T + b1), global_load_lds ------
__global__ __launch_bounds__(256) void gemm1_kernel(
    const unsigned short* __restrict__ xb, const unsigned short* __restrict__ w1b,
    const float* __restrict__ b1, const int* __restrict__ slot_token,
    const int* __restrict__ eoff, unsigned short* __restrict__ h)
{
    __shared__ unsigned short smem[16384];     // As[128*64] + Bs[128*64], unpadded
    __shared__ int tokrow[128];
    unsigned short* As = smem;
    unsigned short* Bs = smem + 8192;

    int e   = blockIdx.z;
    int off = eoff[e], cnt = eoff[NE + e];
    int mt  = blockIdx.y;
    if (mt * 128 >= cnt) return;
    int nB    = blockIdx.x * 128;
    int slot0 = off + mt * 128;
    int valid = cnt - mt * 128; if (valid > 128) valid = 128;

    int tid = threadIdx.x;
    if (tid < 128) {
        int s = slot0 + tid; if (s > NSLOT - 1) s = NSLOT - 1;
        tokrow[tid] = slot_token[s];
    }
    __syncthreads();

    f32x4 acc[16];
    for (int i = 0; i < 16; ++i) acc[i] = (f32x4){0.f, 0.f, 0.f, 0.f};

    const unsigned short* wb = w1b + ((size_t)e * DFF + nB) * DM;
    int wid = tid >> 6, l = tid & 63;
    int wm = (wid & 1) * 64, wn = (wid >> 1) * 64;
    int q = l >> 4, c = l & 15;

    for (int kt = 0; kt < DM / 64; ++kt) {
        // XOR-swizzle source chunk so fragment ds_read_b128 is conflict-free
        for (int j = 0; j < 4; ++j) {
            int u = (wid * 4 + j) * 64 + l;
            int row = u >> 3, sc = (u & 7) ^ (row & 7);
            gload_lds16(xb + (size_t)tokrow[row] * DM + kt * 64 + sc * 8, &As[u * 8]);
        }
        for (int j = 0; j < 4; ++j) {
            int u = (wid * 4 + j) * 64 + l;
            int row = u >> 3, sc = (u & 7) ^ (row & 7);
            gload_lds16(wb + (size_t)row * DM + kt * 64 + sc * 8, &Bs[u * 8]);
        }
        __syncthreads();
        for (int ks = 0; ks < 2; ++ks) {
            int sw = ((ks * 4 + q) ^ (c & 7)) * 8;
            bf16x8 af[4], bv[4];
            for (int i = 0; i < 4; ++i) af[i] = *(bf16x8*)&As[(wm + i * 16 + c) * 64 + sw];
            for (int j = 0; j < 4; ++j) bv[j] = *(bf16x8*)&Bs[(wn + j * 16 + c) * 64 + sw];
            for (int i = 0; i < 4; ++i)
                for (int j = 0; j < 4; ++j)
                    acc[i * 4 + j] = __builtin_amdgcn_mfma_f32_16x16x32_bf16(
                        af[i], bv[j], acc[i * 4 + j], 0, 0, 0);
        }
        __syncthreads();
    }

    // epilogue: bias + exact gelu -> bf16, LDS bounce in 2 row-halves
    float bias[4];
    for (int j = 0; j < 4; ++j) bias[j] = b1[e * DFF + nB + wn + j * 16 + c];
    unsigned short* bounce = smem;             // [64][136] per phase
    for (int ph = 0; ph < 2; ++ph) {
        __syncthreads();
        if ((wid & 1) == ph) {
            for (int i = 0; i < 4; ++i)
                for (int j = 0; j < 4; ++j) {
                    f32x4 a = acc[i * 4 + j];
                    for (int r = 0; r < 4; ++r) {
                        int rl = i * 16 + q * 4 + r;
                        float z = a[r] + bias[j];
                        float g = 0.5f * z * (1.f + erff(z * 0.70710678118654752f));
                        bounce[rl * 136 + wn + j * 16 + c] = f2bf(g);
                    }
                }
        }
        __syncthreads();
        for (int it = 0; it < 4; ++it) {
            int u2 = it * 256 + tid;
            int row = u2 >> 4, ch = u2 & 15;
            int gr = ph * 64 + row;
            if (gr < valid)
                *(us8*)&h[(size_t)(slot0 + gr) * DFF + nB + ch * 8] =
                    *(us8*)&bounce[row * 136 + ch * 8];
        }
    }
}

// ------ GEMM2: out += gate*(h @ w2b^T + b2), K-split x2, atomic out ------
__global__ __launch_bounds__(256) void gemm2_kernel(
    const unsigned short* __restrict__ h, const unsigned short* __restrict__ w2b,
    const float* __restrict__ b2, const int* __restrict__ slot_token,
    const float* __restrict__ slot_gate, const int* __restrict__ eoff,
    float* __restrict__ out)
{
    __shared__ unsigned short smem[16384];
    __shared__ int   tokrow[128];
    __shared__ float grow[128];
    unsigned short* As = smem;
    unsigned short* Bs = smem + 8192;

    int e   = blockIdx.z;
    int off = eoff[e], cnt = eoff[NE + e];
    int mt  = blockIdx.y;
    if (mt * 128 >= cnt) return;
    int nB   = (blockIdx.x & 3) * 128;
    int half = blockIdx.x >> 2;
    int k0   = half * (DFF / 2);
    int slot0 = off + mt * 128;
    int valid = cnt - mt * 128; if (valid > 128) valid = 128;

    int tid = threadIdx.x;
    if (tid < 128) {
        int s = slot0 + tid; if (s > NSLOT - 1) s = NSLOT - 1;
        tokrow[tid] = slot_token[s];
        grow[tid]   = slot_gate[s];
    }
    __syncthreads();

    f32x4 acc[16];
    for (int i = 0; i < 16; ++i) acc[i] = (f32x4){0.f, 0.f, 0.f, 0.f};

    const unsigned short* wb = w2b + ((size_t)e * DM + nB) * DFF;
    int wid = tid >> 6, l = tid & 63;
    int wm = (wid & 1) * 64, wn = (wid >> 1) * 64;
    int q = l >> 4, c = l & 15;

    for (int kt = 0; kt < (DFF / 2) / 64; ++kt) {
        for (int j = 0; j < 4; ++j) {
            int u = (wid * 4 + j) * 64 + l;
            int row = u >> 3, sc = (u & 7) ^ (row & 7);
            size_t s = slot0 + row; if (s > NSLOT - 1) s = NSLOT - 1;
            gload_lds16(h + s * DFF + k0 + kt * 64 + sc * 8, &As[u * 8]);
        }
        for (int j = 0; j < 4; ++j) {
            int u = (wid * 4 + j) * 64 + l;
            int row = u >> 3, sc = (u & 7) ^ (row & 7);
            gload_lds16(wb + (size_t)row * DFF + k0 + kt * 64 + sc * 8, &Bs[u * 8]);
        }
        __syncthreads();
        for (int ks = 0; ks < 2; ++ks) {
            int sw = ((ks * 4 + q) ^ (c & 7)) * 8;
            bf16x8 af[4], bv[4];
            for (int i = 0; i < 4; ++i) af[i] = *(bf16x8*)&As[(wm + i * 16 + c) * 64 + sw];
            for (int j = 0; j < 4; ++j) bv[j] = *(bf16x8*)&Bs[(wn + j * 16 + c) * 64 + sw];
            for (int i = 0; i < 4; ++i)
                for (int j = 0; j < 4; ++j)
                    acc[i * 4 + j] = __builtin_amdgcn_mfma_f32_16x16x32_bf16(
                        af[i], bv[j], acc[i * 4 + j], 0, 0, 0);
        }
        __syncthreads();
    }

    for (int i = 0; i < 4; ++i)
        for (int j = 0; j < 4; ++j) {
            int n = nB + wn + j * 16 + c;
            float bias = (half == 0) ? b2[e * DM + n] : 0.f;
            for (int r = 0; r < 4; ++r) {
                int rl = wm + i * 16 + q * 4 + r;
                if (rl < valid) {
                    float y = acc[i * 4 + j][r] + bias;
                    atomicAdd(&out[(size_t)tokrow[rl] * DM + n], grow[rl] * y);
                }
            }
        }
}

extern "C" void kernel_launch(void* const* d_in, const int* in_sizes, int n_in,
                              void* d_out, int out_size, void* d_ws, size_t ws_size,
                              hipStream_t stream) {
    const float* x  = (const float*)d_in[0];
    const float* rw = (const float*)d_in[1];
    const float* rb = (const float*)d_in[2];
    const float* w1 = (const float*)d_in[3];
    const float* b1 = (const float*)d_in[4];
    const float* w2 = (const float*)d_in[5];
    const float* b2 = (const float*)d_in[6];
    float* out = (float*)d_out;

    char* ws = (char*)d_ws;
    size_t o = 0;
    unsigned short* h   = (unsigned short*)(ws + o); o += (size_t)NSLOT * DFF * 2;
    unsigned short* w1b = (unsigned short*)(ws + o); o += (size_t)NW * 2;
    unsigned short* w2b = (unsigned short*)(ws + o); o += (size_t)NW * 2;
    unsigned short* xb  = (unsigned short*)(ws + o); o += (size_t)T_TOK * DM * 2;
    int*   tok_e      = (int*)(ws + o);   o += (size_t)NSLOT * 4;
    float* tok_g      = (float*)(ws + o); o += (size_t)NSLOT * 4;
    int*   slot_token = (int*)(ws + o);   o += (size_t)NSLOT * 4;
    float* slot_gate  = (float*)(ws + o); o += (size_t)NSLOT * 4;
    int*   eoff       = (int*)(ws + o);

    hipMemsetAsync(d_out, 0, (size_t)T_TOK * DM * 4, stream);
    int conv_blocks = (2 * NW + T_TOK * DM) / 8 / 256;   // 17408, exact
    convert_kernel<<<conv_blocks, 256, 0, stream>>>(w1, w2, x, w1b, w2b, xb);
    router_kernel<<<T_TOK / 4, 256, 0, stream>>>(x, rw, rb, tok_e, tok_g);
    compact_kernel<<<1, 256, 0, stream>>>(tok_e, tok_g, slot_token, slot_gate, eoff);
    gemm1_kernel<<<dim3(DFF / 128, 64, NE), 256, 0, stream>>>(
        xb, w1b, b1, slot_token, eoff, h);
    gemm2_kernel<<<dim3(8, 64, NE), 256, 0, stream>>>(
        h, w2b, b2, slot_token, slot_gate, eoff, out);
}

// Round 3
// 315.773 us; speedup vs baseline: 1.1533x; 1.1533x over previous
//
#include <hip/hip_runtime.h>
#include <stdint.h>

#define T_TOK 4096
#define DM    512
#define DFF   2048
#define NE    16
#define NSLOT (T_TOK * 2)
#define NW    (NE * DFF * DM)   // 16,777,216 elems per weight tensor
#define MAXTILE 80              // max Σ ceil(cnt_e/128) = 79

typedef __attribute__((ext_vector_type(8))) short  bf16x8;
typedef __attribute__((ext_vector_type(4))) float  f32x4;
typedef __attribute__((ext_vector_type(8))) unsigned short us8;

static __device__ __forceinline__ unsigned short f2bf(float f) {
    unsigned int u = __float_as_uint(f);
    u += 0x7FFFu + ((u >> 16) & 1u);   // RNE
    return (unsigned short)(u >> 16);
}

static __device__ __forceinline__ void gload_lds16(const void* g, void* l) {
    __builtin_amdgcn_global_load_lds(
        (const __attribute__((address_space(1))) void*)g,
        (__attribute__((address_space(3))) void*)l, 16, 0, 0);
}

// ------------- convert: w1, w2 fp32 -> bf16 (memory-bound) ---------------
__global__ __launch_bounds__(256) void convert_kernel(
    const float* __restrict__ w1, const float* __restrict__ w2,
    unsigned short* __restrict__ w1b, unsigned short* __restrict__ w2b)
{
    size_t i = ((size_t)blockIdx.x * 256 + threadIdx.x) * 8;
    const float* src; unsigned short* dst;
    if (i < (size_t)NW) { src = w1 + i;        dst = w1b + i; }
    else                { src = w2 + (i - NW); dst = w2b + (i - NW); }
    f32x4 a = *(const f32x4*)src;
    f32x4 b = *(const f32x4*)(src + 4);
    us8 v;
    v[0] = f2bf(a.x); v[1] = f2bf(a.y); v[2] = f2bf(a.z); v[3] = f2bf(a.w);
    v[4] = f2bf(b.x); v[5] = f2bf(b.y); v[6] = f2bf(b.z); v[7] = f2bf(b.w);
    *(us8*)dst = v;
}

// ------- router: fp32 logits, softmax, top-2; also emits x in bf16 -------
__global__ __launch_bounds__(256) void router_kernel(
    const float* __restrict__ x, const float* __restrict__ rw,
    const float* __restrict__ rb, int* __restrict__ tok_e,
    float* __restrict__ tok_g, unsigned short* __restrict__ xb)
{
    __shared__ float rws[NE * DM];
    int tid = threadIdx.x;
    for (int i = 0; i < 8; ++i) {
        int idx = (tid + i * 256) * 4;
        *(f32x4*)&rws[idx] = *(const f32x4*)&rw[idx];
    }
    __syncthreads();

    int wid = tid >> 6, lane = tid & 63;
    int t = blockIdx.x * 4 + wid;

    float xv[8];
    const float* xp = x + (size_t)t * DM + lane * 8;
    *(f32x4*)&xv[0] = *(const f32x4*)xp;
    *(f32x4*)&xv[4] = *(const f32x4*)(xp + 4);

    us8 v;
    for (int i = 0; i < 8; ++i) v[i] = f2bf(xv[i]);
    *(us8*)&xb[(size_t)t * DM + lane * 8] = v;

    float acc[NE];
    for (int e = 0; e < NE; ++e) {
        const float* wp = &rws[e * DM + lane * 8];
        float a = 0.f;
        for (int i = 0; i < 8; ++i) a += xv[i] * wp[i];
        acc[e] = a;
    }
    for (int e = 0; e < NE; ++e) {
        float v2 = acc[e];
        for (int off = 32; off > 0; off >>= 1) v2 += __shfl_xor(v2, off);
        acc[e] = v2 + rb[e];
    }
    float m = acc[0];
    for (int e = 1; e < NE; ++e) m = fmaxf(m, acc[e]);
    float p[NE]; float s = 0.f;
    for (int e = 0; e < NE; ++e) { p[e] = expf(acc[e] - m); s += p[e]; }
    float inv = 1.f / s;
    int i0 = 0; float p0 = p[0];
    for (int e = 1; e < NE; ++e) if (p[e] > p0) { p0 = p[e]; i0 = e; }
    int i1 = (i0 == 0) ? 1 : 0; float p1 = p[i1];
    for (int e = 0; e < NE; ++e)
        if (e != i0 && p[e] > p1) { p1 = p[e]; i1 = e; }
    if (lane == 0) {
        tok_e[t * 2]     = i0;  tok_e[t * 2 + 1] = i1;
        tok_g[t * 2]     = p0 * inv;
        tok_g[t * 2 + 1] = p1 * inv;
    }
}

// -------- compaction: slot lists + tile prefix + token->slot map ---------
// eoff layout: [0..15] row offset, [16..31] count, [32..47] tile_base, [48] total_tiles
__global__ __launch_bounds__(256) void compact_kernel(
    const int* __restrict__ tok_e, int* __restrict__ slot_token,
    int* __restrict__ tok_slot, int* __restrict__ eoff)
{
    __shared__ int cnt[NE], cur[NE];
    int tid = threadIdx.x;
    if (tid < NE) cnt[tid] = 0;
    __syncthreads();
    for (int t = tid; t < T_TOK; t += 256) {
        atomicAdd(&cnt[tok_e[t * 2]], 1);
        atomicAdd(&cnt[tok_e[t * 2 + 1]], 1);
    }
    __syncthreads();
    if (tid == 0) {
        int r = 0, tb = 0;
        for (int e = 0; e < NE; ++e) {
            eoff[e] = r; cur[e] = r; r += cnt[e];
            eoff[16 + e] = cnt[e];
            eoff[32 + e] = tb; tb += (cnt[e] + 127) >> 7;
        }
        eoff[48] = tb;
    }
    __syncthreads();
    for (int t = tid; t < T_TOK; t += 256) {
        for (int k = 0; k < 2; ++k) {
            int e = tok_e[t * 2 + k];
            int s = atomicAdd(&cur[e], 1);
            slot_token[s]     = t;
            tok_slot[t * 2 + k] = s;
        }
    }
}

// ------ GEMM1: h = gelu(x_bf[gather] @ w1b^T + b1), dense tile grid ------
__global__ __launch_bounds__(256) void gemm1_kernel(
    const unsigned short* __restrict__ xb, const unsigned short* __restrict__ w1b,
    const float* __restrict__ b1, const int* __restrict__ slot_token,
    const int* __restrict__ eoff, unsigned short* __restrict__ h)
{
    __shared__ unsigned short smem[16384];     // As[128*64] + Bs[128*64]
    __shared__ int tokrow[128];
    __shared__ int meta[49];
    unsigned short* As = smem;
    unsigned short* Bs = smem + 8192;

    int tid = threadIdx.x;
    if (tid < 49) meta[tid] = eoff[tid];
    __syncthreads();

    int slot_idx = blockIdx.y;
    if (slot_idx >= meta[48]) return;
    int e = 0;
    while (e < NE - 1 && meta[32 + e + 1] <= slot_idx) ++e;
    int mt  = slot_idx - meta[32 + e];
    int off = meta[e], cnt = meta[16 + e];
    int nB    = blockIdx.x * 128;
    int slot0 = off + mt * 128;
    int valid = cnt - mt * 128; if (valid > 128) valid = 128;

    if (tid < 128) {
        int s = slot0 + tid; if (s > NSLOT - 1) s = NSLOT - 1;
        tokrow[tid] = slot_token[s];
    }
    __syncthreads();

    f32x4 acc[16];
    for (int i = 0; i < 16; ++i) acc[i] = (f32x4){0.f, 0.f, 0.f, 0.f};

    const unsigned short* wb = w1b + ((size_t)e * DFF + nB) * DM;
    int wid = tid >> 6, l = tid & 63;
    int wm = (wid & 1) * 64, wn = (wid >> 1) * 64;
    int q = l >> 4, c = l & 15;

    for (int kt = 0; kt < DM / 64; ++kt) {
        for (int j = 0; j < 4; ++j) {
            int u = (wid * 4 + j) * 64 + l;
            int row = u >> 3, sc = (u & 7) ^ (row & 7);
            gload_lds16(xb + (size_t)tokrow[row] * DM + kt * 64 + sc * 8, &As[u * 8]);
        }
        for (int j = 0; j < 4; ++j) {
            int u = (wid * 4 + j) * 64 + l;
            int row = u >> 3, sc = (u & 7) ^ (row & 7);
            gload_lds16(wb + (size_t)row * DM + kt * 64 + sc * 8, &Bs[u * 8]);
        }
        __syncthreads();
        for (int ks = 0; ks < 2; ++ks) {
            int sw = ((ks * 4 + q) ^ (c & 7)) * 8;
            bf16x8 af[4], bv[4];
            for (int i = 0; i < 4; ++i) af[i] = *(bf16x8*)&As[(wm + i * 16 + c) * 64 + sw];
            for (int j = 0; j < 4; ++j) bv[j] = *(bf16x8*)&Bs[(wn + j * 16 + c) * 64 + sw];
            for (int i = 0; i < 4; ++i)
                for (int j = 0; j < 4; ++j)
                    acc[i * 4 + j] = __builtin_amdgcn_mfma_f32_16x16x32_bf16(
                        af[i], bv[j], acc[i * 4 + j], 0, 0, 0);
        }
        __syncthreads();
    }

    float bias[4];
    for (int j = 0; j < 4; ++j) bias[j] = b1[e * DFF + nB + wn + j * 16 + c];
    unsigned short* bounce = smem;             // [64][136] per phase
    for (int ph = 0; ph < 2; ++ph) {
        __syncthreads();
        if ((wid & 1) == ph) {
            for (int i = 0; i < 4; ++i)
                for (int j = 0; j < 4; ++j) {
                    f32x4 a = acc[i * 4 + j];
                    for (int r = 0; r < 4; ++r) {
                        int rl = i * 16 + q * 4 + r;
                        float z = a[r] + bias[j];
                        float g = 0.5f * z * (1.f + erff(z * 0.70710678118654752f));
                        bounce[rl * 136 + wn + j * 16 + c] = f2bf(g);
                    }
                }
        }
        __syncthreads();
        for (int it = 0; it < 4; ++it) {
            int u2 = it * 256 + tid;
            int row = u2 >> 4, ch = u2 & 15;
            int gr = ph * 64 + row;
            if (gr < valid)
                *(us8*)&h[(size_t)(slot0 + gr) * DFF + nB + ch * 8] =
                    *(us8*)&bounce[row * 136 + ch * 8];
        }
    }
}

// ------ GEMM2: y[slot] = h @ w2b^T (no bias/gate), plain stores ----------
__global__ __launch_bounds__(256) void gemm2_kernel(
    const unsigned short* __restrict__ h, const unsigned short* __restrict__ w2b,
    const int* __restrict__ eoff, float* __restrict__ y)
{
    __shared__ unsigned short smem[16384];
    __shared__ int meta[49];
    unsigned short* As = smem;
    unsigned short* Bs = smem + 8192;

    int tid = threadIdx.x;
    if (tid < 49) meta[tid] = eoff[tid];
    __syncthreads();

    int slot_idx = blockIdx.y;
    if (slot_idx >= meta[48]) return;
    int e = 0;
    while (e < NE - 1 && meta[32 + e + 1] <= slot_idx) ++e;
    int mt  = slot_idx - meta[32 + e];
    int off = meta[e], cnt = meta[16 + e];
    int nB    = blockIdx.x * 128;
    int slot0 = off + mt * 128;
    int valid = cnt - mt * 128; if (valid > 128) valid = 128;

    f32x4 acc[16];
    for (int i = 0; i < 16; ++i) acc[i] = (f32x4){0.f, 0.f, 0.f, 0.f};

    const unsigned short* wb = w2b + ((size_t)e * DM + nB) * DFF;
    int wid = tid >> 6, l = tid & 63;
    int wm = (wid & 1) * 64, wn = (wid >> 1) * 64;
    int q = l >> 4, c = l & 15;

    for (int kt = 0; kt < DFF / 64; ++kt) {
        for (int j = 0; j < 4; ++j) {
            int u = (wid * 4 + j) * 64 + l;
            int row = u >> 3, sc = (u & 7) ^ (row & 7);
            size_t s = slot0 + row; if (s > NSLOT - 1) s = NSLOT - 1;
            gload_lds16(h + s * DFF + kt * 64 + sc * 8, &As[u * 8]);
        }
        for (int j = 0; j < 4; ++j) {
            int u = (wid * 4 + j) * 64 + l;
            int row = u >> 3, sc = (u & 7) ^ (row & 7);
            gload_lds16(wb + (size_t)row * DFF + kt * 64 + sc * 8, &Bs[u * 8]);
        }
        __syncthreads();
        for (int ks = 0; ks < 2; ++ks) {
            int sw = ((ks * 4 + q) ^ (c & 7)) * 8;
            bf16x8 af[4], bv[4];
            for (int i = 0; i < 4; ++i) af[i] = *(bf16x8*)&As[(wm + i * 16 + c) * 64 + sw];
            for (int j = 0; j < 4; ++j) bv[j] = *(bf16x8*)&Bs[(wn + j * 16 + c) * 64 + sw];
            for (int i = 0; i < 4; ++i)
                for (int j = 0; j < 4; ++j)
                    acc[i * 4 + j] = __builtin_amdgcn_mfma_f32_16x16x32_bf16(
                        af[i], bv[j], acc[i * 4 + j], 0, 0, 0);
        }
        __syncthreads();
    }

    for (int i = 0; i < 4; ++i)
        for (int j = 0; j < 4; ++j) {
            int n = nB + wn + j * 16 + c;
            for (int r = 0; r < 4; ++r) {
                int rl = wm + i * 16 + q * 4 + r;
                if (rl < valid)
                    y[(size_t)(slot0 + rl) * DM + n] = acc[i * 4 + j][r];
            }
        }
}

// ---- combine: out[t] = g0*(y[s0]+b2[e0]) + g1*(y[s1]+b2[e1]) ------------
__global__ __launch_bounds__(256) void combine_kernel(
    const float* __restrict__ y, const float* __restrict__ b2,
    const int* __restrict__ tok_slot, const float* __restrict__ tok_g,
    const int* __restrict__ tok_e, float* __restrict__ out)
{
    int tid = threadIdx.x;
    int t = blockIdx.x * 2 + (tid >> 7);
    int d = (tid & 127) * 4;
    int s0 = tok_slot[t * 2], s1 = tok_slot[t * 2 + 1];
    float g0 = tok_g[t * 2], g1 = tok_g[t * 2 + 1];
    int e0 = tok_e[t * 2], e1 = tok_e[t * 2 + 1];
    f32x4 y0 = *(const f32x4*)&y[(size_t)s0 * DM + d];
    f32x4 y1 = *(const f32x4*)&y[(size_t)s1 * DM + d];
    f32x4 c0 = *(const f32x4*)&b2[e0 * DM + d];
    f32x4 c1 = *(const f32x4*)&b2[e1 * DM + d];
    f32x4 o;
    for (int i = 0; i < 4; ++i) o[i] = g0 * (y0[i] + c0[i]) + g1 * (y1[i] + c1[i]);
    *(f32x4*)&out[(size_t)t * DM + d] = o;
}

extern "C" void kernel_launch(void* const* d_in, const int* in_sizes, int n_in,
                              void* d_out, int out_size, void* d_ws, size_t ws_size,
                              hipStream_t stream) {
    const float* x  = (const float*)d_in[0];
    const float* rw = (const float*)d_in[1];
    const float* rb = (const float*)d_in[2];
    const float* w1 = (const float*)d_in[3];
    const float* b1 = (const float*)d_in[4];
    const float* w2 = (const float*)d_in[5];
    const float* b2 = (const float*)d_in[6];
    float* out = (float*)d_out;

    char* ws = (char*)d_ws;
    size_t o = 0;
    unsigned short* h   = (unsigned short*)(ws + o); o += (size_t)NSLOT * DFF * 2;
    unsigned short* w1b = (unsigned short*)(ws + o); o += (size_t)NW * 2;
    unsigned short* w2b = (unsigned short*)(ws + o); o += (size_t)NW * 2;
    unsigned short* xb  = (unsigned short*)(ws + o); o += (size_t)T_TOK * DM * 2;
    int*   tok_e      = (int*)(ws + o);   o += (size_t)NSLOT * 4;
    float* tok_g      = (float*)(ws + o); o += (size_t)NSLOT * 4;
    int*   tok_slot   = (int*)(ws + o);   o += (size_t)NSLOT * 4;
    int*   slot_token = (int*)(ws + o);   o += (size_t)NSLOT * 4;
    int*   eoff       = (int*)(ws + o);
    // y aliases w1b: gemm1 (last reader of w1b) completes before gemm2 writes y
    float* y = (float*)w1b;

    convert_kernel<<<2 * NW / 8 / 256, 256, 0, stream>>>(w1, w2, w1b, w2b);
    router_kernel<<<T_TOK / 4, 256, 0, stream>>>(x, rw, rb, tok_e, tok_g, xb);
    compact_kernel<<<1, 256, 0, stream>>>(tok_e, slot_token, tok_slot, eoff);
    gemm1_kernel<<<dim3(DFF / 128, MAXTILE), 256, 0, stream>>>(
        xb, w1b, b1, slot_token, eoff, h);
    gemm2_kernel<<<dim3(DM / 128, MAXTILE), 256, 0, stream>>>(
        h, w2b, eoff, y);
    combine_kernel<<<T_TOK / 2, 256, 0, stream>>>(
        y, b2, tok_slot, tok_g, tok_e, out);
}